// Round 2
// baseline (531.352 us; speedup 1.0000x reference)
//
#include <hip/hip_runtime.h>

// cluster_layer: q[n,k] = (1/(1+||x_n - c_k||^2)) normalized over k  (alpha=1)
// N=1e6, D=64, K=20.
//
// History:
//  R2: 1 row/thread, 16 dwordx4/row, c via SGPR operands. 153 us, 1546 GB/s
//      (19% peak). VGPR=64 -> RA sank the x loads; latency-bound.
//  R3: sched_barrier pin under launch_bounds(256,4). Only ~6 us gained: the
//      128-VGPR cap made RA split xv live ranges anyway; one-shot blocks also
//      eat an HBM-latency bubble at every ramp.
//  R4: persistent grid-stride, 2 rows/thread/iter, launch_bounds(256,2) so the
//      allocator has 256 VGPRs and keeps BOTH row buffers (32 dwordx4 = 32 KB
//      in flight per wave). Each scalar c-chunk now feeds 160 FMAs (halved
//      lgkm-wait density). NT stores keep the 80 MB out-stream from evicting
//      x in L3. Target: HBM roofline ~55-70 us kernel.

#define NPTS  1000000
#define DIM   64
#define KCL   20
#define BLOCK 256
#define GRID  512            // 2 blocks/CU on 256 CUs -> persistent

typedef float f32x4 __attribute__((ext_vector_type(4)));

__global__ __launch_bounds__(BLOCK, 2) void cluster_q_kernel(
    const float* __restrict__ x,
    const float* __restrict__ c,
    float* __restrict__ out)
{
    __shared__ float sCsq[KCL];

    // per-block csq (tiny: 20 lanes x 64 reads, c is L2-hot after block 0)
    if (threadIdx.x < KCL) {
        float s = 0.f;
        #pragma unroll
        for (int j = 0; j < DIM; ++j) {
            float v = c[threadIdx.x * DIM + j];
            s += v * v;
        }
        sCsq[threadIdx.x] = s;
    }
    __syncthreads();

    const int tid = blockIdx.x * BLOCK + threadIdx.x;
    const int T   = GRID * BLOCK;   // 131072 threads; stride between the 2 rows

    for (int base = tid; base < NPTS; base += 2 * T) {
        const int  row0 = base;
        const int  row1 = base + T;
        const bool has1 = (row1 < NPTS);

        // Two coalesced 1 KB/wave streams; 32 dwordx4 in flight per wave.
        const f32x4* __restrict__ xa =
            (const f32x4*)x + (size_t)row0 * (DIM / 4);
        const f32x4* __restrict__ xb =
            (const f32x4*)x + (size_t)(has1 ? row1 : row0) * (DIM / 4);

        f32x4 av[DIM / 4], bv[DIM / 4];
        #pragma unroll
        for (int m = 0; m < DIM / 4; ++m) av[m] = xa[m];
        #pragma unroll
        for (int m = 0; m < DIM / 4; ++m) bv[m] = xb[m];
        // Keep all 32 loads issued before any consumer (no sinking).
        __builtin_amdgcn_sched_barrier(0);

        float acc0[KCL], acc1[KCL];
        #pragma unroll
        for (int k = 0; k < KCL; ++k) { acc0[k] = 0.f; acc1[k] = 0.f; }
        float xsq0 = 0.f, xsq1 = 0.f;

        // c indices are compile-time constants on a uniform pointer -> s_load
        // -> SGPR operand in v_fma. Each 80-value c chunk feeds 160 FMAs.
        #pragma unroll
        for (int m = 0; m < DIM / 4; ++m) {
            xsq0 += av[m].x * av[m].x + av[m].y * av[m].y
                  + av[m].z * av[m].z + av[m].w * av[m].w;
            xsq1 += bv[m].x * bv[m].x + bv[m].y * bv[m].y
                  + bv[m].z * bv[m].z + bv[m].w * bv[m].w;
            #pragma unroll
            for (int k = 0; k < KCL; ++k) {
                const float c0 = c[k * DIM + 4 * m + 0];
                const float c1 = c[k * DIM + 4 * m + 1];
                const float c2 = c[k * DIM + 4 * m + 2];
                const float c3 = c[k * DIM + 4 * m + 3];
                acc0[k] += av[m].x * c0 + av[m].y * c1
                         + av[m].z * c2 + av[m].w * c3;
                acc1[k] += bv[m].x * c0 + bv[m].y * c1
                         + bv[m].z * c2 + bv[m].w * c3;
            }
        }

        // epilogue row0: d2 -> q -> normalize -> 5 NT float4 stores
        {
            float s = 0.f;
            #pragma unroll
            for (int k = 0; k < KCL; ++k) {
                float d2 = xsq0 + sCsq[k] - 2.0f * acc0[k];
                float qq = __builtin_amdgcn_rcpf(1.0f + d2);
                acc0[k] = qq;
                s += qq;
            }
            const float inv = __builtin_amdgcn_rcpf(s);
            f32x4* o4 = (f32x4*)(out + (size_t)row0 * KCL);
            #pragma unroll
            for (int k = 0; k < KCL; k += 4) {
                f32x4 v;
                v.x = acc0[k + 0] * inv;
                v.y = acc0[k + 1] * inv;
                v.z = acc0[k + 2] * inv;
                v.w = acc0[k + 3] * inv;
                __builtin_nontemporal_store(v, &o4[k / 4]);
            }
        }
        // epilogue row1
        if (has1) {
            float s = 0.f;
            #pragma unroll
            for (int k = 0; k < KCL; ++k) {
                float d2 = xsq1 + sCsq[k] - 2.0f * acc1[k];
                float qq = __builtin_amdgcn_rcpf(1.0f + d2);
                acc1[k] = qq;
                s += qq;
            }
            const float inv = __builtin_amdgcn_rcpf(s);
            f32x4* o4 = (f32x4*)(out + (size_t)row1 * KCL);
            #pragma unroll
            for (int k = 0; k < KCL; k += 4) {
                f32x4 v;
                v.x = acc1[k + 0] * inv;
                v.y = acc1[k + 1] * inv;
                v.z = acc1[k + 2] * inv;
                v.w = acc1[k + 3] * inv;
                __builtin_nontemporal_store(v, &o4[k / 4]);
            }
        }
    }
}

extern "C" void kernel_launch(void* const* d_in, const int* in_sizes, int n_in,
                              void* d_out, int out_size, void* d_ws, size_t ws_size,
                              hipStream_t stream) {
    const float* x = (const float*)d_in[0];   // (N, D) fp32
    const float* c = (const float*)d_in[1];   // (K, D) fp32
    float* out = (float*)d_out;               // (N, K) fp32

    cluster_q_kernel<<<GRID, BLOCK, 0, stream>>>(x, c, out);
}

// Round 3
// 390.149 us; speedup vs baseline: 1.3619x; 1.3619x over previous
//
#include <hip/hip_runtime.h>

// cluster_layer: q[n,k] = (1/(1+||x_n - c_k||^2)) normalized over k  (alpha=1)
// N=1e6, D=64, K=20.
//
// History:
//  R2: 1 row/thread, 16 dwordx4/row, c via uniform (SGPR) operands, one-shot
//      grid. 153 us kernel, 1546 GB/s (19%), VALUBusy 67%.
//  R3: sched_barrier pin. +6 us only — RA splits xv live ranges under the
//      128-VGPR cap; forcing MLP from source loses to the allocator.
//  R4: persistent 2-rows/thread + NT stores. REGRESSION 275 us: VGPR=92 (RA
//      still sank loads), NT stores amplified WRITE 79->195 MB (80 B rows
//      share 128 B lines; L2 write-back coalesces, NT doesn't), occupancy 21%.
//  R5: halve VALU issue via packed fp32 (v_pk_fma_f32): float2 formulation,
//      42 instrs per 16-B chunk instead of 84 (672/row). Keep R2's proven
//      shell: one-shot grid, 1 row/thread, short live ranges (low VGPR ->
//      8 waves/SIMD TLP hides HBM+smem latency), plain float4 stores.

#define NPTS 1000000
#define DIM  64
#define KCL  20
#define BLOCK 256

typedef float f32x2 __attribute__((ext_vector_type(2)));
typedef float f32x4 __attribute__((ext_vector_type(4)));

__global__ __launch_bounds__(BLOCK, 4) void cluster_q_kernel(
    const float* __restrict__ x,
    const float* __restrict__ c,
    float* __restrict__ out)
{
    __shared__ float sCsq[KCL];

    // per-block csq (tiny: 20 lanes x 64 reads, c is L2-hot after block 0)
    if (threadIdx.x < KCL) {
        float s = 0.f;
        #pragma unroll
        for (int j = 0; j < DIM; ++j) {
            float v = c[threadIdx.x * DIM + j];
            s += v * v;
        }
        sCsq[threadIdx.x] = s;
    }
    __syncthreads();

    const int row = blockIdx.x * BLOCK + threadIdx.x;
    if (row >= NPTS) return;

    const f32x4* __restrict__ x4 = (const f32x4*)x + (size_t)row * (DIM / 4);
    // c viewed as float2: uniform pointer + compile-time indices -> s_load,
    // even element offsets -> aligned SGPR pairs feeding v_pk_fma_f32.
    const f32x2* __restrict__ c2 = (const f32x2*)c;

    // float2 accumulators: each v_pk_fma_f32 does 2 fp32 MACs.
    f32x2 acc[KCL];
    #pragma unroll
    for (int k = 0; k < KCL; ++k) acc[k] = (f32x2){0.f, 0.f};
    f32x2 xsq2 = (f32x2){0.f, 0.f};

    #pragma unroll
    for (int m = 0; m < DIM / 4; ++m) {
        const f32x4 xv = x4[m];                  // one dwordx4, short live range
        const f32x2 xlo = (f32x2){xv.x, xv.y};
        const f32x2 xhi = (f32x2){xv.z, xv.w};
        xsq2 += xlo * xlo;                       // pk_fma
        xsq2 += xhi * xhi;                       // pk_fma
        #pragma unroll
        for (int k = 0; k < KCL; ++k) {
            const int base = (k * DIM + 4 * m) / 2;   // compile-time constant
            acc[k] += xlo * c2[base];                 // pk_fma, SGPR-pair src
            acc[k] += xhi * c2[base + 1];             // pk_fma, SGPR-pair src
        }
    }

    // epilogue: d2 -> q -> normalize -> 5 aligned float4 stores
    const float xsq = xsq2.x + xsq2.y;
    float qv[KCL];
    float s = 0.f;
    #pragma unroll
    for (int k = 0; k < KCL; ++k) {
        const float cross = acc[k].x + acc[k].y;
        const float d2 = xsq + sCsq[k] - 2.0f * cross;
        const float qq = __builtin_amdgcn_rcpf(1.0f + d2);   // v_rcp_f32
        qv[k] = qq;
        s += qq;
    }
    const float inv = __builtin_amdgcn_rcpf(s);

    f32x4* o4 = (f32x4*)(out + (size_t)row * KCL);
    #pragma unroll
    for (int k = 0; k < KCL; k += 4) {
        f32x4 v;
        v.x = qv[k + 0] * inv;
        v.y = qv[k + 1] * inv;
        v.z = qv[k + 2] * inv;
        v.w = qv[k + 3] * inv;
        o4[k / 4] = v;            // plain store: L2 write-back merges lines
    }
}

extern "C" void kernel_launch(void* const* d_in, const int* in_sizes, int n_in,
                              void* d_out, int out_size, void* d_ws, size_t ws_size,
                              hipStream_t stream) {
    const float* x = (const float*)d_in[0];   // (N, D) fp32
    const float* c = (const float*)d_in[1];   // (K, D) fp32
    float* out = (float*)d_out;               // (N, K) fp32

    const int blocks = (NPTS + BLOCK - 1) / BLOCK;   // 3907
    cluster_q_kernel<<<blocks, BLOCK, 0, stream>>>(x, c, out);
}

// Round 4
// 371.678 us; speedup vs baseline: 1.4296x; 1.0497x over previous
//
#include <hip/hip_runtime.h>

// cluster_layer: q[n,k] = (1/(1+||x_n - c_k||^2)) normalized over k  (alpha=1)
// N=1e6, D=64, K=20.
//
// History:
//  R2: 1 row/thread, 16 dwordx4/row, c via SGPR operands. 153 us, 1546 GB/s
//      (19%), VGPR=64 -> RA sank x loads to ~4-deep; latency-bound.
//  R3: sched_barrier pin. +6 us. Scheduler != allocator: RA re-sank loads.
//  R4: persistent 2-row + NT stores. REGRESSION (WRITE 79->195 MB, occ 21%).
//  R5: v_pk_fma_f32 (half the VALU issue). +0 -> VALU-issue NOT binding.
//  R6: the stall is ~85% of block lifetime = 16 dependent chunk-loads at
//      ~500-900 cy each with only ~4 in flight. Force 16-deep MLP with
//      inline-asm: one volatile asm block issues all 16 global_load_dwordx4
//      (RA cannot sink/split asm defs -> 64 VGPRs live), then each chunk is
//      consumed behind "s_waitcnt vmcnt(15-m)" tied through a "+v" operand
//      (the wait DEFINES the value the FMAs read -> correct ordering without
//      sched_barrier; c s_loads remain free to hoist across steps).
//      launch_bounds(256,2): 256-VGPR budget so asm outputs never spill
//      (spilling a not-yet-arrived load result would store garbage).

#define NPTS 1000000
#define DIM  64
#define KCL  20
#define BLOCK 256

typedef float f32x4 __attribute__((ext_vector_type(4)));

__global__ __launch_bounds__(BLOCK, 2) void cluster_q_kernel(
    const float* __restrict__ x,
    const float* __restrict__ c,
    float* __restrict__ out)
{
    __shared__ float sCsq[KCL];

    // per-block csq (tiny: 20 lanes x 64 reads, c is L2-hot after block 0)
    if (threadIdx.x < KCL) {
        float s = 0.f;
        #pragma unroll
        for (int j = 0; j < DIM; ++j) {
            float v = c[threadIdx.x * DIM + j];
            s += v * v;
        }
        sCsq[threadIdx.x] = s;
    }
    __syncthreads();

    const int row = blockIdx.x * BLOCK + threadIdx.x;
    if (row >= NPTS) return;

    const float* px = x + (size_t)row * DIM;   // 256 B per row, 16-B aligned

    // ---- 16 loads, one volatile asm block: issued back-to-back, all live ----
    f32x4 x0, x1, x2, x3, x4, x5, x6, x7, x8, x9, x10, x11, x12, x13, x14, x15;
    asm volatile(
        "global_load_dwordx4 %0,  %16, off\n\t"
        "global_load_dwordx4 %1,  %16, off offset:16\n\t"
        "global_load_dwordx4 %2,  %16, off offset:32\n\t"
        "global_load_dwordx4 %3,  %16, off offset:48\n\t"
        "global_load_dwordx4 %4,  %16, off offset:64\n\t"
        "global_load_dwordx4 %5,  %16, off offset:80\n\t"
        "global_load_dwordx4 %6,  %16, off offset:96\n\t"
        "global_load_dwordx4 %7,  %16, off offset:112\n\t"
        "global_load_dwordx4 %8,  %16, off offset:128\n\t"
        "global_load_dwordx4 %9,  %16, off offset:144\n\t"
        "global_load_dwordx4 %10, %16, off offset:160\n\t"
        "global_load_dwordx4 %11, %16, off offset:176\n\t"
        "global_load_dwordx4 %12, %16, off offset:192\n\t"
        "global_load_dwordx4 %13, %16, off offset:208\n\t"
        "global_load_dwordx4 %14, %16, off offset:224\n\t"
        "global_load_dwordx4 %15, %16, off offset:240"
        : "=v"(x0), "=v"(x1), "=v"(x2), "=v"(x3),
          "=v"(x4), "=v"(x5), "=v"(x6), "=v"(x7),
          "=v"(x8), "=v"(x9), "=v"(x10), "=v"(x11),
          "=v"(x12), "=v"(x13), "=v"(x14), "=v"(x15)
        : "v"(px));

    float acc[KCL];
    #pragma unroll
    for (int k = 0; k < KCL; ++k) acc[k] = 0.f;
    float xsq = 0.f;

    // Consume chunk M once vmcnt <= 15-M (loads retire in order). The wait
    // asm reads+writes the chunk register, so every FMA on it is data-
    // dependent on the wait -> scheduler cannot hoist consumers above it.
#define STEP(M, XV, VM)                                               \
    asm volatile("s_waitcnt vmcnt(" #VM ")" : "+v"(XV));              \
    xsq += XV.x * XV.x + XV.y * XV.y + XV.z * XV.z + XV.w * XV.w;     \
    _Pragma("unroll")                                                 \
    for (int k = 0; k < KCL; ++k) {                                   \
        acc[k] += XV.x * c[k * DIM + 4 * (M) + 0]                     \
                + XV.y * c[k * DIM + 4 * (M) + 1]                     \
                + XV.z * c[k * DIM + 4 * (M) + 2]                     \
                + XV.w * c[k * DIM + 4 * (M) + 3];                    \
    }

    STEP(0,  x0,  15)
    STEP(1,  x1,  14)
    STEP(2,  x2,  13)
    STEP(3,  x3,  12)
    STEP(4,  x4,  11)
    STEP(5,  x5,  10)
    STEP(6,  x6,  9)
    STEP(7,  x7,  8)
    STEP(8,  x8,  7)
    STEP(9,  x9,  6)
    STEP(10, x10, 5)
    STEP(11, x11, 4)
    STEP(12, x12, 3)
    STEP(13, x13, 2)
    STEP(14, x14, 1)
    STEP(15, x15, 0)
#undef STEP

    // epilogue: d2 -> q -> normalize -> 5 aligned float4 stores
    float s = 0.f;
    #pragma unroll
    for (int k = 0; k < KCL; ++k) {
        const float d2 = xsq + sCsq[k] - 2.0f * acc[k];
        const float qq = __builtin_amdgcn_rcpf(1.0f + d2);   // v_rcp_f32
        acc[k] = qq;
        s += qq;
    }
    const float inv = __builtin_amdgcn_rcpf(s);

    f32x4* o4 = (f32x4*)(out + (size_t)row * KCL);
    #pragma unroll
    for (int k = 0; k < KCL; k += 4) {
        f32x4 v;
        v.x = acc[k + 0] * inv;
        v.y = acc[k + 1] * inv;
        v.z = acc[k + 2] * inv;
        v.w = acc[k + 3] * inv;
        o4[k / 4] = v;            // plain store: L2 write-back merges lines
    }
}

extern "C" void kernel_launch(void* const* d_in, const int* in_sizes, int n_in,
                              void* d_out, int out_size, void* d_ws, size_t ws_size,
                              hipStream_t stream) {
    const float* x = (const float*)d_in[0];   // (N, D) fp32
    const float* c = (const float*)d_in[1];   // (K, D) fp32
    float* out = (float*)d_out;               // (N, K) fp32

    const int blocks = (NPTS + BLOCK - 1) / BLOCK;   // 3907
    cluster_q_kernel<<<blocks, BLOCK, 0, stream>>>(x, c, out);
}